// Round 3
// baseline (300.506 us; speedup 1.0000x reference)
//
#include <hip/hip_runtime.h>
#include <stdint.h>

#define B_  4
#define T_  2048
#define C_  1024
#define H_  16
#define HS_ 64
#define M_  (B_*T_)   // 8192
#define K_  C_        // 1024

typedef unsigned short u16;
typedef float v4f __attribute__((ext_vector_type(4)));
typedef short v8s __attribute__((ext_vector_type(8)));
typedef u16   v4u __attribute__((ext_vector_type(4)));
typedef unsigned int u32;
typedef u32 v2u32 __attribute__((ext_vector_type(2)));

__device__ __forceinline__ u16 f2bf(float f){
  unsigned u = __float_as_uint(f);
  u += 0x7fffu + ((u >> 16) & 1u);          // round-to-nearest-even
  return (u16)(u >> 16);
}

// pack two f32 -> one u32 of 2x bf16 (lo = a, hi = b), single HW instruction
__device__ __forceinline__ u32 cvt_pk_bf16(float a, float b){
  u32 r;
  asm("v_cvt_pk_bf16_f32 %0, %1, %2" : "=v"(r) : "v"(a), "v"(b));
  return r;
}

__device__ __forceinline__ void async16(const void* g, void* l){
  __builtin_amdgcn_global_load_lds(
      (const __attribute__((address_space(1))) unsigned int*)g,
      (__attribute__((address_space(3))) unsigned int*)l,
      16, 0, 0);
}

// ---------------- f32 -> bf16 conversion (4 elems/thread)
__global__ void conv_f32_bf16(const float* __restrict__ src, u16* __restrict__ dst){
  int i = (blockIdx.x * 256 + threadIdx.x) * 4;
  v4f v = *(const v4f*)(src + i);
  v4u o;
  #pragma unroll
  for (int j = 0; j < 4; j++) o[j] = f2bf(v[j]);
  *(v4u*)(dst + i) = o;
}

// ---------------- weight transpose: 3x (H,C,HS) f32 -> bf16 WallT[n][c], n = tensor*1024 + h*64 + d
__global__ void transpose_w(const float* __restrict__ Wq, const float* __restrict__ Wk,
                            const float* __restrict__ Wv, u16* __restrict__ wallT){
  int idx = blockIdx.x * 256 + threadIdx.x;      // 3072*1024 threads
  int n = idx >> 10, c = idx & 1023;
  int tensor = n >> 10;
  int h = (n >> 6) & 15;
  int d = n & 63;
  const float* W = (tensor == 0) ? Wq : ((tensor == 1) ? Wk : Wv);
  wallT[idx] = f2bf(W[((size_t)(h * C_ + c)) * HS_ + d]);
}

// Q pre-scale: scores use exp2(q.k * 0.125 * log2(e)) -> fold into Q once.
#define QSCALE 0.1803368801111204f

// ---------------- GEMM  out(M x N) = A(M x K) * Bt(N x K)^T  (A, Bt bf16; fp32 acc)
template<int MODE>
__global__ __launch_bounds__(256)
void gemm_bt(const u16* __restrict__ A, const u16* __restrict__ Bt,
             const float* __restrict__ bias,
             u16* __restrict__ o0, u16* __restrict__ o1, u16* __restrict__ o2,
             float* __restrict__ o0f)
{
  __shared__ __align__(16) u16 sA[128 * 32];
  __shared__ __align__(16) u16 sB[128 * 32];
  const int tid  = threadIdx.x;
  const int lane = tid & 63;
  const int wave = tid >> 6;
  const int l15  = lane & 15, quad = lane >> 4;
  const int wm   = wave >> 1, wn = wave & 1;
  const int m0   = blockIdx.y * 128;
  const int n0   = blockIdx.x * 128;

  v4f acc[4][4] = {};

  const int L0 = tid * 16;
  const int r0 = L0 >> 6, c0 = L0 & 63;
  const int L1 = (256 + tid) * 16;
  const int r1 = L1 >> 6, c1 = L1 & 63;

  const char* Ab = (const char*)A;
  const char* Bb = (const char*)Bt;

  for (int kk = 0; kk < K_; kk += 32){
    async16(Ab + ((size_t)(m0 + r0) * K_ + kk) * 2 + c0, (char*)sA + L0);
    async16(Ab + ((size_t)(m0 + r1) * K_ + kk) * 2 + c1, (char*)sA + L1);
    async16(Bb + ((size_t)(n0 + r0) * K_ + kk) * 2 + c0, (char*)sB + L0);
    async16(Bb + ((size_t)(n0 + r1) * K_ + kk) * 2 + c1, (char*)sB + L1);
    __syncthreads();

    v8s af[4], bfr[4];
    #pragma unroll
    for (int mi = 0; mi < 4; mi++)
      af[mi] = *(const v8s*)(sA + (wm * 64 + mi * 16 + l15) * 32 + quad * 8);
    #pragma unroll
    for (int ni = 0; ni < 4; ni++)
      bfr[ni] = *(const v8s*)(sB + (wn * 64 + ni * 16 + l15) * 32 + quad * 8);

    #pragma unroll
    for (int mi = 0; mi < 4; mi++)
      #pragma unroll
      for (int ni = 0; ni < 4; ni++)
        acc[mi][ni] = __builtin_amdgcn_mfma_f32_16x16x32_bf16(af[mi], bfr[ni], acc[mi][ni], 0, 0, 0);
    __syncthreads();
  }

  if constexpr (MODE == 0){
    #pragma unroll
    for (int ni = 0; ni < 4; ni++){
      const int ng = n0 + wn * 64 + ni * 16 + l15;
      const int tensor = ng >> 10;
      const int hh = (ng >> 6) & 15;
      const int d  = ng & 63;
      #pragma unroll
      for (int mi = 0; mi < 4; mi++){
        const int mbase = m0 + wm * 64 + mi * 16 + quad * 4;
        const int bb = mbase >> 11;
        const int tt = mbase & 2047;
        if (tensor == 2){
          v4u pk;
          #pragma unroll
          for (int r = 0; r < 4; r++) pk[r] = f2bf(acc[mi][ni][r]);
          *(v4u*)(o2 + ((size_t)((bb * H_ + hh) * HS_ + d)) * T_ + tt) = pk;   // vT: contiguous in t
        } else if (tensor == 0){
          #pragma unroll
          for (int r = 0; r < 4; r++)
            o0[((size_t)((bb * H_ + hh)) * T_ + tt + r) * HS_ + d] = f2bf(acc[mi][ni][r] * QSCALE);
        } else {
          #pragma unroll
          for (int r = 0; r < 4; r++)
            o1[((size_t)((bb * H_ + hh)) * T_ + tt + r) * HS_ + d] = f2bf(acc[mi][ni][r]);
        }
      }
    }
  } else {
    #pragma unroll
    for (int ni = 0; ni < 4; ni++){
      const int ng = n0 + wn * 64 + ni * 16 + l15;
      const float bv = bias[ng];
      #pragma unroll
      for (int mi = 0; mi < 4; mi++){
        const int mbase = m0 + wm * 64 + mi * 16 + quad * 4;
        #pragma unroll
        for (int r = 0; r < 4; r++)
          o0f[(size_t)(mbase + r) * C_ + ng] = acc[mi][ni][r] + bv;   // f32 output
      }
    }
  }
}

// ---------------- flash attention v7: 2 q-fragments per wave to amortize K/V LDS reads.
// v6 analysis: LDS READ BW is the pipe -- each wave re-read the full 64x64 K and V
// tiles (16 KB) to cover only 16 q-rows => ~53 us of pure LDS-pipe time (85 B/cyc b128).
// v7: 4 waves x 32 q-rows (two 16-row fragments a,b). kf/vf are read ONCE per nt and
// feed both fragments' MFMAs => 24 KB LDS reads per 32 rows (was 40 KB). Everything
// else (staging pattern, swizzles, swapped-QK^T softmax, P round-trip) is unchanged.
// 512 blocks x 256 thr, 36 KB LDS => 4 blocks/CU = 16 waves/CU (same occupancy as v6).
// s_setprio(1) around MFMA clusters (T5: +4-7% in this independent-block regime).
__global__ __launch_bounds__(256, 4)
void attn(const u16* __restrict__ Q, const u16* __restrict__ Kb_, const u16* __restrict__ Vt,
          u16* __restrict__ O)
{
  __shared__ __align__(16) u16 sK[64 * 64];       // [t][d-swizzled]  8 KB
  __shared__ __align__(16) u16 sV[64 * 64];       // [d][t-swizzled]  8 KB
  __shared__ __align__(16) u16 Plds[4][32][80];   // per-wave P [frag*16+q][k], 160B row stride
  const int tid  = threadIdx.x;                   // 0..255
  const int lane = tid & 63;
  const int wave = tid >> 6;                      // 0..3
  const int l15  = lane & 15, quad = lane >> 4;
  const int pp   = blockIdx.y & 7;                // pair index 0..7 over 16 q-tiles of 128
  const int bh   = blockIdx.x * 8 + (blockIdx.y >> 3);  // XCD-grouped b*H+h

  const u16* Qb = Q   + (size_t)bh * T_ * HS_;
  const u16* Kb = Kb_ + (size_t)bh * T_ * HS_;
  const u16* Vb = Vt  + (size_t)bh * HS_ * T_;    // vT: [d][t]
  const int b = bh >> 4, h = bh & 15;

  // staging geometry: granule g (16 B); 256 threads stage two K + two V granules.
  // K granule (t, c): LDS slot t*8 + (c ^ (t&7)); source K[k0+t][c*8..]
  // V granule (d, c): LDS slot d*8 + (c ^ (d&7)); source vT[d][k0 + c*8..]
  const int g0 = tid, g1 = tid + 256;
  const int t0g = g0 >> 3, t1g = g1 >> 3;
  const int sw0 = ((g0 & 7) ^ (t0g & 7)) << 4;
  const int sw1 = ((g1 & 7) ^ (t1g & 7)) << 4;
  const char* Kby = (const char*)Kb;
  const char* Vby = (const char*)Vb;
  const int koff0 = t0g * 128 + sw0,        koff1 = t1g * 128 + sw1;
  const int voff0 = t0g * (T_ * 2) + sw0,   voff1 = t1g * (T_ * 2) + sw1;
  char* sKp0 = (char*)sK + g0 * 16;  char* sKp1 = (char*)sK + g1 * 16;
  char* sVp0 = (char*)sV + g0 * 16;  char* sVp1 = (char*)sV + g1 * 16;

  // swizzled frag offsets (elements) within an sK/sV row
  const int fsw0 = (quad ^ (l15 & 7)) * 8;        // granule d8=quad   (k = quad*8+j)
  const int fsw1 = ((quad + 4) ^ (l15 & 7)) * 8;  // granule d8=quad+4 (k = 32+quad*8+j)

  #pragma unroll 1
  for (int ph = 0; ph < 2; ph++){
    const int qt = ph ? (15 - pp) : pp;           // q-tile (128 rows) 0..15
    const int q0a = qt * 128 + wave * 32;         // fragment a rows
    const int q0b = q0a + 16;                     // fragment b rows

    // Q fragments (m/n=l15, k=quad*8+j), pre-scaled by QSCALE at projection
    const v8s qf0a = *(const v8s*)(Qb + (size_t)(q0a + l15) * HS_ + quad * 8);
    const v8s qf1a = *(const v8s*)(Qb + (size_t)(q0a + l15) * HS_ + 32 + quad * 8);
    const v8s qf0b = *(const v8s*)(Qb + (size_t)(q0b + l15) * HS_ + quad * 8);
    const v8s qf1b = *(const v8s*)(Qb + (size_t)(q0b + l15) * HS_ + 32 + quad * 8);

    v4f Oaa[4] = {}, Oab[4] = {};
    float lsumA = 0.f, lsumB = 0.f;               // partial sums for rows q0a+l15 / q0b+l15

    const int ktmax = 2 * qt + 1;                 // kv-tiles (64 keys) covering q-tile
    for (int kt = 0; kt <= ktmax; kt++){
      const int k0 = kt * 64;
      // ---- stage K,V tiles (once per block)
      async16(Kby + (size_t)k0 * 128 + koff0, sKp0);
      async16(Kby + (size_t)k0 * 128 + koff1, sKp1);
      async16(Vby + (size_t)k0 * 2   + voff0, sVp0);
      async16(Vby + (size_t)k0 * 2   + voff1, sVp1);
      __syncthreads();

      // waves whose rows are entirely left of this kv-tile contribute nothing
      if (k0 <= q0b + 15){
        const bool actA = (k0 <= q0a + 15);       // wave-uniform

        // ---- S^T = K Q^T : C/D col(l15)=q-row, row(quad*4+reg)=k-pos
        v4f sa[4] = {}, sb[4] = {};
        __builtin_amdgcn_s_setprio(1);
        #pragma unroll
        for (int nt = 0; nt < 4; nt++){
          const u16* kr = sK + (nt * 16 + l15) * 64;
          v8s kf0 = *(const v8s*)(kr + fsw0);
          v8s kf1 = *(const v8s*)(kr + fsw1);
          sb[nt] = __builtin_amdgcn_mfma_f32_16x16x32_bf16(kf0, qf0b, sb[nt], 0, 0, 0);
          sb[nt] = __builtin_amdgcn_mfma_f32_16x16x32_bf16(kf1, qf1b, sb[nt], 0, 0, 0);
          if (actA){
            sa[nt] = __builtin_amdgcn_mfma_f32_16x16x32_bf16(kf0, qf0a, sa[nt], 0, 0, 0);
            sa[nt] = __builtin_amdgcn_mfma_f32_16x16x32_bf16(kf1, qf1a, sa[nt], 0, 0, 0);
          }
        }
        __builtin_amdgcn_s_setprio(0);

        // ---- p = 2^s, causal mask (diag tiles only), scalar row-sum, packed P write
        {
          const bool diagB = (k0 + 63 > q0b);
          const int qrelB = (q0b - k0) + l15;
          #pragma unroll
          for (int nt = 0; nt < 4; nt++){
            float p0 = exp2f(sb[nt][0]);
            float p1 = exp2f(sb[nt][1]);
            float p2 = exp2f(sb[nt][2]);
            float p3 = exp2f(sb[nt][3]);
            if (diagB){
              const int kbase = nt * 16 + quad * 4;
              if (kbase + 0 > qrelB) p0 = 0.f;
              if (kbase + 1 > qrelB) p1 = 0.f;
              if (kbase + 2 > qrelB) p2 = 0.f;
              if (kbase + 3 > qrelB) p3 = 0.f;
            }
            lsumB += (p0 + p1) + (p2 + p3);
            v2u32 w;
            w[0] = cvt_pk_bf16(p0, p1);
            w[1] = cvt_pk_bf16(p2, p3);
            *(v2u32*)&Plds[wave][16 + l15][nt * 16 + quad * 4] = w;
          }
        }
        if (actA){
          const bool diagA = (k0 + 63 > q0a);
          const int qrelA = (q0a - k0) + l15;
          #pragma unroll
          for (int nt = 0; nt < 4; nt++){
            float p0 = exp2f(sa[nt][0]);
            float p1 = exp2f(sa[nt][1]);
            float p2 = exp2f(sa[nt][2]);
            float p3 = exp2f(sa[nt][3]);
            if (diagA){
              const int kbase = nt * 16 + quad * 4;
              if (kbase + 0 > qrelA) p0 = 0.f;
              if (kbase + 1 > qrelA) p1 = 0.f;
              if (kbase + 2 > qrelA) p2 = 0.f;
              if (kbase + 3 > qrelA) p3 = 0.f;
            }
            lsumA += (p0 + p1) + (p2 + p3);
            v2u32 w;
            w[0] = cvt_pk_bf16(p0, p1);
            w[1] = cvt_pk_bf16(p2, p3);
            *(v2u32*)&Plds[wave][l15][nt * 16 + quad * 4] = w;
          }
        }

        // ---- P: [q][k] -> A fragments via per-wave LDS round-trip (same-wave, in-order DS)
        asm volatile("" ::: "memory");
        const v8s pf0b = *(const v8s*)&Plds[wave][16 + l15][quad * 8];
        const v8s pf1b = *(const v8s*)&Plds[wave][16 + l15][32 + quad * 8];
        v8s pf0a, pf1a;
        if (actA){
          pf0a = *(const v8s*)&Plds[wave][l15][quad * 8];
          pf1a = *(const v8s*)&Plds[wave][l15][32 + quad * 8];
        }
        __builtin_amdgcn_s_setprio(1);
        #pragma unroll
        for (int nt = 0; nt < 4; nt++){
          const u16* vr = sV + (nt * 16 + l15) * 64;
          v8s vf0 = *(const v8s*)(vr + fsw0);
          v8s vf1 = *(const v8s*)(vr + fsw1);
          Oab[nt] = __builtin_amdgcn_mfma_f32_16x16x32_bf16(pf0b, vf0, Oab[nt], 0, 0, 0);
          Oab[nt] = __builtin_amdgcn_mfma_f32_16x16x32_bf16(pf1b, vf1, Oab[nt], 0, 0, 0);
          if (actA){
            Oaa[nt] = __builtin_amdgcn_mfma_f32_16x16x32_bf16(pf0a, vf0, Oaa[nt], 0, 0, 0);
            Oaa[nt] = __builtin_amdgcn_mfma_f32_16x16x32_bf16(pf1a, vf1, Oaa[nt], 0, 0, 0);
          }
        }
        __builtin_amdgcn_s_setprio(0);
      }
      __syncthreads();   // everyone done reading sK/sV before next stage overwrites
    }

    // row-sum finalize per fragment: quads hold disjoint k-ranges -> combine, redistribute
    {
      float rs = lsumB;
      rs += __shfl_xor(rs, 16);
      rs += __shfl_xor(rs, 32);
      #pragma unroll
      for (int reg = 0; reg < 4; reg++){
        const float rsq = __shfl(rs, quad * 4 + reg);
        const float inv = (rsq > 0.f) ? (1.f / rsq) : 0.f;
        const int t = q0b + quad * 4 + reg;
        #pragma unroll
        for (int nt = 0; nt < 4; nt++)
          O[((size_t)(b * T_ + t)) * C_ + h * HS_ + nt * 16 + l15] = f2bf(Oab[nt][reg] * inv);
      }
    }
    {
      float rs = lsumA;
      rs += __shfl_xor(rs, 16);
      rs += __shfl_xor(rs, 32);
      #pragma unroll
      for (int reg = 0; reg < 4; reg++){
        const float rsq = __shfl(rs, quad * 4 + reg);
        const float inv = (rsq > 0.f) ? (1.f / rsq) : 0.f;
        const int t = q0a + quad * 4 + reg;
        #pragma unroll
        for (int nt = 0; nt < 4; nt++)
          O[((size_t)(b * T_ + t)) * C_ + h * HS_ + nt * 16 + l15] = f2bf(Oaa[nt][reg] * inv);
      }
    }
  }
}

extern "C" void kernel_launch(void* const* d_in, const int* in_sizes, int n_in,
                              void* d_out, int out_size, void* d_ws, size_t ws_size,
                              hipStream_t stream)
{
  const float* x     = (const float*)d_in[0];
  const float* Wq    = (const float*)d_in[1];
  const float* Wk    = (const float*)d_in[2];
  const float* Wv    = (const float*)d_in[3];
  const float* Wproj = (const float*)d_in[4];
  const float* bproj = (const float*)d_in[5];
  float* out = (float*)d_out;   // f32 output

  u16* xhat   = (u16*)d_ws;                       // (B*T, C)    dead after gemm<0>
  u16* att    = xhat;                             // (B*T, C)    written by attn
  u16* q_ws   = xhat  + (size_t)M_ * C_;
  u16* k_ws   = q_ws  + (size_t)M_ * C_;
  u16* vt_ws  = k_ws  + (size_t)M_ * C_;
  u16* wallT  = vt_ws + (size_t)M_ * C_;          // (3072,1024)
  u16* wprojT = wallT + (size_t)3 * C_ * K_;      // (1024,1024)

  conv_f32_bf16<<<dim3((M_ * C_) / 1024), dim3(256), 0, stream>>>(x, xhat);
  transpose_w<<<dim3((3 * C_ * K_) / 256), dim3(256), 0, stream>>>(Wq, Wk, Wv, wallT);
  conv_f32_bf16<<<dim3((C_ * C_) / 1024), dim3(256), 0, stream>>>(Wproj, wprojT);
  gemm_bt<0><<<dim3(24, 64), dim3(256), 0, stream>>>(xhat, wallT, nullptr,
                                                     q_ws, k_ws, vt_ws, nullptr);
  attn<<<dim3(8, 64), dim3(256), 0, stream>>>(q_ws, k_ws, vt_ws, att);
  gemm_bt<1><<<dim3(8, 64), dim3(256), 0, stream>>>(att, wprojT, bproj,
                                                    nullptr, nullptr, nullptr, out);
}

// Round 4
// 272.433 us; speedup vs baseline: 1.1030x; 1.1030x over previous
//
#include <hip/hip_runtime.h>
#include <stdint.h>

#define B_  4
#define T_  2048
#define C_  1024
#define H_  16
#define HS_ 64
#define M_  (B_*T_)   // 8192
#define K_  C_        // 1024

typedef unsigned short u16;
typedef float v4f __attribute__((ext_vector_type(4)));
typedef short v8s __attribute__((ext_vector_type(8)));
typedef u16   v4u __attribute__((ext_vector_type(4)));
typedef unsigned int u32;
typedef u32 v2u32 __attribute__((ext_vector_type(2)));

__device__ __forceinline__ u16 f2bf(float f){
  unsigned u = __float_as_uint(f);
  u += 0x7fffu + ((u >> 16) & 1u);          // round-to-nearest-even
  return (u16)(u >> 16);
}

// pack two f32 -> one u32 of 2x bf16 (lo = a, hi = b), single HW instruction
__device__ __forceinline__ u32 cvt_pk_bf16(float a, float b){
  u32 r;
  asm("v_cvt_pk_bf16_f32 %0, %1, %2" : "=v"(r) : "v"(a), "v"(b));
  return r;
}

__device__ __forceinline__ void async16(const void* g, void* l){
  __builtin_amdgcn_global_load_lds(
      (const __attribute__((address_space(1))) unsigned int*)g,
      (__attribute__((address_space(3))) unsigned int*)l,
      16, 0, 0);
}

// ---------------- f32 -> bf16 conversion (4 elems/thread)
__global__ void conv_f32_bf16(const float* __restrict__ src, u16* __restrict__ dst){
  int i = (blockIdx.x * 256 + threadIdx.x) * 4;
  v4f v = *(const v4f*)(src + i);
  v4u o;
  #pragma unroll
  for (int j = 0; j < 4; j++) o[j] = f2bf(v[j]);
  *(v4u*)(dst + i) = o;
}

// ---------------- weight transpose: 3x (H,C,HS) f32 -> bf16 WallT[n][c], n = tensor*1024 + h*64 + d
__global__ void transpose_w(const float* __restrict__ Wq, const float* __restrict__ Wk,
                            const float* __restrict__ Wv, u16* __restrict__ wallT){
  int idx = blockIdx.x * 256 + threadIdx.x;      // 3072*1024 threads
  int n = idx >> 10, c = idx & 1023;
  int tensor = n >> 10;
  int h = (n >> 6) & 15;
  int d = n & 63;
  const float* W = (tensor == 0) ? Wq : ((tensor == 1) ? Wk : Wv);
  wallT[idx] = f2bf(W[((size_t)(h * C_ + c)) * HS_ + d]);
}

// Q pre-scale: scores use exp2(q.k * 0.125 * log2(e)) -> fold into Q once.
#define QSCALE 0.1803368801111204f

// ---------------- GEMM  out(M x N) = A(M x K) * Bt(N x K)^T  (A, Bt bf16; fp32 acc)
// v2: T3-minimum 2-phase double-buffer. Prefetch next K-tile's global_load_lds BEFORE
// this tile's ds_read+MFMA; ONE __syncthreads per K-step (its vmcnt(0) drain lands
// after ~16 MFMAs of overlap instead of right after issue). 32 KB LDS -> 5 blocks/CU.
template<int MODE>
__global__ __launch_bounds__(256)
void gemm_bt(const u16* __restrict__ A, const u16* __restrict__ Bt,
             const float* __restrict__ bias,
             u16* __restrict__ o0, u16* __restrict__ o1, u16* __restrict__ o2,
             float* __restrict__ o0f)
{
  __shared__ __align__(16) u16 sA[2][128 * 32];
  __shared__ __align__(16) u16 sB[2][128 * 32];
  const int tid  = threadIdx.x;
  const int lane = tid & 63;
  const int wave = tid >> 6;
  const int l15  = lane & 15, quad = lane >> 4;
  const int wm   = wave >> 1, wn = wave & 1;
  const int m0   = blockIdx.y * 128;
  const int n0   = blockIdx.x * 128;

  v4f acc[4][4] = {};

  const int L0 = tid * 16;
  const int r0 = L0 >> 6, c0 = L0 & 63;
  const int L1 = (256 + tid) * 16;
  const int r1 = L1 >> 6, c1 = L1 & 63;

  const char* Ab = (const char*)A;
  const char* Bb = (const char*)Bt;

  // prologue: stage K-tile 0 into buffer 0
  async16(Ab + ((size_t)(m0 + r0) * K_) * 2 + c0, (char*)sA[0] + L0);
  async16(Ab + ((size_t)(m0 + r1) * K_) * 2 + c1, (char*)sA[0] + L1);
  async16(Bb + ((size_t)(n0 + r0) * K_) * 2 + c0, (char*)sB[0] + L0);
  async16(Bb + ((size_t)(n0 + r1) * K_) * 2 + c1, (char*)sB[0] + L1);
  __syncthreads();

  int cur = 0;
  for (int kk = 0; kk < K_; kk += 32){
    const int nxt = cur ^ 1;
    if (kk + 32 < K_){
      const int k2 = kk + 32;
      async16(Ab + ((size_t)(m0 + r0) * K_ + k2) * 2 + c0, (char*)sA[nxt] + L0);
      async16(Ab + ((size_t)(m0 + r1) * K_ + k2) * 2 + c1, (char*)sA[nxt] + L1);
      async16(Bb + ((size_t)(n0 + r0) * K_ + k2) * 2 + c0, (char*)sB[nxt] + L0);
      async16(Bb + ((size_t)(n0 + r1) * K_ + k2) * 2 + c1, (char*)sB[nxt] + L1);
    }

    v8s af[4], bfr[4];
    #pragma unroll
    for (int mi = 0; mi < 4; mi++)
      af[mi] = *(const v8s*)(sA[cur] + (wm * 64 + mi * 16 + l15) * 32 + quad * 8);
    #pragma unroll
    for (int ni = 0; ni < 4; ni++)
      bfr[ni] = *(const v8s*)(sB[cur] + (wn * 64 + ni * 16 + l15) * 32 + quad * 8);

    #pragma unroll
    for (int mi = 0; mi < 4; mi++)
      #pragma unroll
      for (int ni = 0; ni < 4; ni++)
        acc[mi][ni] = __builtin_amdgcn_mfma_f32_16x16x32_bf16(af[mi], bfr[ni], acc[mi][ni], 0, 0, 0);

    __syncthreads();   // drains prefetch vmcnt + guards buffer swap (one barrier/K-step)
    cur = nxt;
  }

  if constexpr (MODE == 0){
    #pragma unroll
    for (int ni = 0; ni < 4; ni++){
      const int ng = n0 + wn * 64 + ni * 16 + l15;
      const int tensor = ng >> 10;
      const int hh = (ng >> 6) & 15;
      const int d  = ng & 63;
      #pragma unroll
      for (int mi = 0; mi < 4; mi++){
        const int mbase = m0 + wm * 64 + mi * 16 + quad * 4;
        const int bb = mbase >> 11;
        const int tt = mbase & 2047;
        if (tensor == 2){
          v4u pk;
          #pragma unroll
          for (int r = 0; r < 4; r++) pk[r] = f2bf(acc[mi][ni][r]);
          *(v4u*)(o2 + ((size_t)((bb * H_ + hh) * HS_ + d)) * T_ + tt) = pk;   // vT: contiguous in t
        } else if (tensor == 0){
          #pragma unroll
          for (int r = 0; r < 4; r++)
            o0[((size_t)((bb * H_ + hh)) * T_ + tt + r) * HS_ + d] = f2bf(acc[mi][ni][r] * QSCALE);
        } else {
          #pragma unroll
          for (int r = 0; r < 4; r++)
            o1[((size_t)((bb * H_ + hh)) * T_ + tt + r) * HS_ + d] = f2bf(acc[mi][ni][r]);
        }
      }
    }
  } else {
    #pragma unroll
    for (int ni = 0; ni < 4; ni++){
      const int ng = n0 + wn * 64 + ni * 16 + l15;
      const float bv = bias[ng];
      #pragma unroll
      for (int mi = 0; mi < 4; mi++){
        const int mbase = m0 + wm * 64 + mi * 16 + quad * 4;
        #pragma unroll
        for (int r = 0; r < 4; r++)
          o0f[(size_t)(mbase + r) * C_ + ng] = acc[mi][ni][r] + bv;   // f32 output
      }
    }
  }
}

// ---------------- flash attention v6 (reverted from v7): swapped QK^T (S^T layout).
// v7 post-mortem: 32 rows/wave halves total wave count (2048 waves = 8/CU) ->
// occupancy 35.5->19.6%, staging latency exposed, attn 83->93 us. At this problem
// size (B*H=64) 16 rows/wave x 4096 waves = 16 waves/CU is the sweet spot.
__global__ __launch_bounds__(512, 4)
void attn(const u16* __restrict__ Q, const u16* __restrict__ Kb_, const u16* __restrict__ Vt,
          u16* __restrict__ O)
{
  __shared__ __align__(16) u16 sK[64 * 64];       // [t][d-swizzled]  8 KB
  __shared__ __align__(16) u16 sV[64 * 64];       // [d][t-swizzled]  8 KB
  __shared__ __align__(16) u16 Plds[8][16][80];   // per-wave P tile [q][k], 160B row stride
  const int tid  = threadIdx.x;                   // 0..511
  const int lane = tid & 63;
  const int wave = tid >> 6;                      // 0..7
  const int l15  = lane & 15, quad = lane >> 4;
  const int pp   = blockIdx.y & 7;                // pair index 0..7 over 16 q-tiles of 128
  const int bh   = blockIdx.x * 8 + (blockIdx.y >> 3);  // XCD-grouped b*H+h

  const u16* Qb = Q   + (size_t)bh * T_ * HS_;
  const u16* Kb = Kb_ + (size_t)bh * T_ * HS_;
  const u16* Vb = Vt  + (size_t)bh * HS_ * T_;    // vT: [d][t]
  const int b = bh >> 4, h = bh & 15;

  // staging geometry: granule g (16 B); 512 threads stage one K granule + one V granule.
  // K granule (t, c): LDS slot t*8 + (c ^ (t&7)); source K[k0+t][c*8..]
  // V granule (d, c): LDS slot d*8 + (c ^ (d&7)); source vT[d][k0 + c*8..]
  const int g  = tid;
  const int tg = g >> 3;                          // row 0..63
  const int sw = ((g & 7) ^ (tg & 7)) << 4;
  const char* Kby = (const char*)Kb;
  const char* Vby = (const char*)Vb;
  const int koff = tg * 128 + sw;
  const int voff = tg * (T_ * 2) + sw;
  char* sKp = (char*)sK + g * 16;
  char* sVp = (char*)sV + g * 16;

  // swizzled frag offsets (elements) within an sK/sV row
  const int fsw0 = (quad ^ (l15 & 7)) * 8;        // granule d8=quad   (k = quad*8+j)
  const int fsw1 = ((quad + 4) ^ (l15 & 7)) * 8;  // granule d8=quad+4 (k = 32+quad*8+j)

  #pragma unroll 1
  for (int ph = 0; ph < 2; ph++){
    const int qt = ph ? (15 - pp) : pp;           // q-tile (128 rows) 0..15
    const int q0 = qt * 128 + wave * 16;          // this wave's 16 q-rows

    // Q fragments (m/n=l15, k=quad*8+j), pre-scaled by QSCALE at projection
    const v8s qf0 = *(const v8s*)(Qb + (size_t)(q0 + l15) * HS_ + quad * 8);
    const v8s qf1 = *(const v8s*)(Qb + (size_t)(q0 + l15) * HS_ + 32 + quad * 8);

    v4f Oa[4] = {};
    float lsum = 0.f;                             // partial sum for q-row q0+l15

    const int ktmax = 2 * qt + 1;                 // kv-tiles (64 keys) covering q-tile
    for (int kt = 0; kt <= ktmax; kt++){
      const int k0 = kt * 64;
      // ---- stage K,V tiles (once per block)
      async16(Kby + (size_t)k0 * 128 + koff, sKp);
      async16(Vby + (size_t)k0 * 2   + voff, sVp);
      __syncthreads();

      // waves whose rows are entirely left of this kv-tile contribute nothing
      if (k0 <= q0 + 15){
        // ---- S^T = K Q^T : C/D col(l15)=q-row, row(quad*4+reg)=k-pos
        v4f sacc[4] = {};
        #pragma unroll
        for (int nt = 0; nt < 4; nt++){
          const u16* kr = sK + (nt * 16 + l15) * 64;
          v8s kf0 = *(const v8s*)(kr + fsw0);
          v8s kf1 = *(const v8s*)(kr + fsw1);
          sacc[nt] = __builtin_amdgcn_mfma_f32_16x16x32_bf16(kf0, qf0, sacc[nt], 0, 0, 0);
          sacc[nt] = __builtin_amdgcn_mfma_f32_16x16x32_bf16(kf1, qf1, sacc[nt], 0, 0, 0);
        }
        const bool diag = (k0 + 63 > q0);         // masking possible in this tile
        const int qrow_rel = (q0 - k0) + l15;     // mask when nt*16+quad*4+r > qrow_rel

        // ---- p = 2^s, causal mask (diag tiles only), scalar row-sum, packed P write
        #pragma unroll
        for (int nt = 0; nt < 4; nt++){
          float p0 = exp2f(sacc[nt][0]);
          float p1 = exp2f(sacc[nt][1]);
          float p2 = exp2f(sacc[nt][2]);
          float p3 = exp2f(sacc[nt][3]);
          if (diag){
            const int kbase = nt * 16 + quad * 4;
            if (kbase + 0 > qrow_rel) p0 = 0.f;
            if (kbase + 1 > qrow_rel) p1 = 0.f;
            if (kbase + 2 > qrow_rel) p2 = 0.f;
            if (kbase + 3 > qrow_rel) p3 = 0.f;
          }
          lsum += (p0 + p1) + (p2 + p3);
          v2u32 w;
          w[0] = cvt_pk_bf16(p0, p1);
          w[1] = cvt_pk_bf16(p2, p3);
          *(v2u32*)&Plds[wave][l15][nt * 16 + quad * 4] = w;   // one b64 store
        }

        // ---- P: [q][k] -> A fragments via per-wave LDS round-trip (same-wave, in-order DS)
        asm volatile("" ::: "memory");
        const v8s pf0 = *(const v8s*)&Plds[wave][l15][quad * 8];
        const v8s pf1 = *(const v8s*)&Plds[wave][l15][32 + quad * 8];
        #pragma unroll
        for (int nt = 0; nt < 4; nt++){
          const u16* vr = sV + (nt * 16 + l15) * 64;
          v8s vf0 = *(const v8s*)(vr + fsw0);
          v8s vf1 = *(const v8s*)(vr + fsw1);
          Oa[nt] = __builtin_amdgcn_mfma_f32_16x16x32_bf16(pf0, vf0, Oa[nt], 0, 0, 0);
          Oa[nt] = __builtin_amdgcn_mfma_f32_16x16x32_bf16(pf1, vf1, Oa[nt], 0, 0, 0);
        }
      }
      __syncthreads();   // everyone done reading sK/sV before next stage overwrites
    }

    // row-sum finalize: quads hold disjoint k-ranges of row q0+l15 -> combine, redistribute
    float rs = lsum;
    rs += __shfl_xor(rs, 16);
    rs += __shfl_xor(rs, 32);                     // every lane: full sum for row q0+l15
    #pragma unroll
    for (int reg = 0; reg < 4; reg++){
      const float rsq = __shfl(rs, quad * 4 + reg);   // sum for row q0+quad*4+reg
      const float inv = (rsq > 0.f) ? (1.f / rsq) : 0.f;
      const int t = q0 + quad * 4 + reg;
      #pragma unroll
      for (int nt = 0; nt < 4; nt++)
        O[((size_t)(b * T_ + t)) * C_ + h * HS_ + nt * 16 + l15] = f2bf(Oa[nt][reg] * inv);
    }
  }
}

extern "C" void kernel_launch(void* const* d_in, const int* in_sizes, int n_in,
                              void* d_out, int out_size, void* d_ws, size_t ws_size,
                              hipStream_t stream)
{
  const float* x     = (const float*)d_in[0];
  const float* Wq    = (const float*)d_in[1];
  const float* Wk    = (const float*)d_in[2];
  const float* Wv    = (const float*)d_in[3];
  const float* Wproj = (const float*)d_in[4];
  const float* bproj = (const float*)d_in[5];
  float* out = (float*)d_out;   // f32 output

  u16* xhat   = (u16*)d_ws;                       // (B*T, C)    dead after gemm<0>
  u16* att    = xhat;                             // (B*T, C)    written by attn
  u16* q_ws   = xhat  + (size_t)M_ * C_;
  u16* k_ws   = q_ws  + (size_t)M_ * C_;
  u16* vt_ws  = k_ws  + (size_t)M_ * C_;
  u16* wallT  = vt_ws + (size_t)M_ * C_;          // (3072,1024)
  u16* wprojT = wallT + (size_t)3 * C_ * K_;      // (1024,1024)

  conv_f32_bf16<<<dim3((M_ * C_) / 1024), dim3(256), 0, stream>>>(x, xhat);
  transpose_w<<<dim3((3 * C_ * K_) / 256), dim3(256), 0, stream>>>(Wq, Wk, Wv, wallT);
  conv_f32_bf16<<<dim3((C_ * C_) / 1024), dim3(256), 0, stream>>>(Wproj, wprojT);
  gemm_bt<0><<<dim3(24, 64), dim3(256), 0, stream>>>(xhat, wallT, nullptr,
                                                     q_ws, k_ws, vt_ws, nullptr);
  attn<<<dim3(8, 64), dim3(512), 0, stream>>>(q_ws, k_ws, vt_ws, att);
  gemm_bt<1><<<dim3(8, 64), dim3(256), 0, stream>>>(att, wprojT, bproj,
                                                    nullptr, nullptr, nullptr, out);
}